// Round 15
// baseline (206.338 us; speedup 1.0000x reference)
//
#include <hip/hip_runtime.h>

#define N_NODES 100000
#define N_EDGES 1600000
#define HID 64
#define BN_EPS 1e-5f

// ---- fused gather+gemm1: 64 nodes/block, 16 per wave, barrier-free ----
#define GG_BLOCKS ((N_NODES + 63) / 64)              // 1563
#define STAT_ROWS (GG_BLOCKS * 4)                    // per-wave stats rows

// ---- MFMA tiling: 16-row tiles ----
#define ROW_TILES (N_NODES / 16)                     // 6250 (exact)
#define TPW2 2                                       // tiles/wave, bn_gemm & fused jk
#define G2_BLOCKS ((ROW_TILES + 4*TPW2 - 1) / (4*TPW2))   // 782

// ---- stats two-stage reduction ----
#define SR_BLOCKS 64

// ---- multi-split CSR build parameters ----
#define NB 391                              // coarse buckets of 256 nodes (dst>>8)
#define MS_BLOCKS 1000
#define MS_EPB (N_EDGES / MS_BLOCKS)        // 1600 edges per block
#define MS_CNT (NB * MS_BLOCKS)             // 391000 segment counters
#define GS_CHUNK 512
#define GS_BLOCKS ((MS_CNT + GS_CHUNK - 1) / GS_CHUNK)   // 764

// ---- prep kernel block ranges ----
#define CVT_B 3125                          // FEAT/8/256
#define WT_B 112                            // (12288+16384)/256
#define PREP_BLOCKS (CVT_B + WT_B + MS_BLOCKS)

#define LDS_STRIDE 72                        // bf16 elems; 144B rows, 16B-aligned

typedef __bf16 bf16x8 __attribute__((ext_vector_type(8)));
typedef float  f32x4  __attribute__((ext_vector_type(4)));
typedef unsigned short u16x8 __attribute__((ext_vector_type(8)));

__device__ __forceinline__ float bf2f(unsigned short u) {
    return __uint_as_float(((unsigned)u) << 16);
}
__device__ __forceinline__ unsigned short f2bf_rne(float f) {
    unsigned u = __float_as_uint(f);
    u += 0x7FFFu + ((u >> 16) & 1u);
    return (unsigned short)(u >> 16);
}

// ---------------- prep: x->bf16 cvt + weight transposes + msplit hist ----------------
__global__ __launch_bounds__(256) void prep_kernel(
        const float* __restrict__ x, unsigned short* __restrict__ xb,
        const float* __restrict__ Wjk,
        const float* __restrict__ W1_0, const float* __restrict__ W2_0,
        const float* __restrict__ W1_1, const float* __restrict__ W2_1,
        unsigned short* __restrict__ wjk_t,
        unsigned short* __restrict__ w1t_0, unsigned short* __restrict__ w2t_0,
        unsigned short* __restrict__ w1t_1, unsigned short* __restrict__ w2t_1,
        const int* __restrict__ dst, int* __restrict__ cnt) {
    __shared__ int h[NB];
    const int b = blockIdx.x;
    if (b < CVT_B) {
        size_t i = ((size_t)b * 256 + threadIdx.x) * 8;
        float4 a = *reinterpret_cast<const float4*>(x + i);
        float4 c = *reinterpret_cast<const float4*>(x + i + 4);
        ushort4 w0 = make_ushort4(f2bf_rne(a.x), f2bf_rne(a.y), f2bf_rne(a.z), f2bf_rne(a.w));
        ushort4 w1 = make_ushort4(f2bf_rne(c.x), f2bf_rne(c.y), f2bf_rne(c.z), f2bf_rne(c.w));
        *reinterpret_cast<ushort4*>(xb + i) = w0;
        *reinterpret_cast<ushort4*>(xb + i + 4) = w1;
    } else if (b < CVT_B + WT_B) {
        int i = (b - CVT_B) * 256 + threadIdx.x;
        if (i < 12288) {
            int c = i / 192, k = i - c * 192;
            wjk_t[i] = f2bf_rne(Wjk[k * 64 + c]);
        } else {
            int r = i - 12288;
            int which = r >> 12, rem = r & 4095;
            int c = rem >> 6, k = rem & 63;
            const float* W = (which == 0) ? W1_0 : (which == 1) ? W2_0
                           : (which == 2) ? W1_1 : W2_1;
            unsigned short* Wt = (which == 0) ? w1t_0 : (which == 1) ? w2t_0
                               : (which == 2) ? w1t_1 : w2t_1;
            Wt[rem] = f2bf_rne(W[k * 64 + c]);
        }
    } else {
        const int hb = b - CVT_B - WT_B;
        for (int i = threadIdx.x; i < NB; i += 256) h[i] = 0;
        __syncthreads();
        const int e0 = hb * MS_EPB;
        for (int e = e0 + threadIdx.x; e < e0 + MS_EPB; e += 256)
            atomicAdd(&h[dst[e] >> 8], 1);
        __syncthreads();
        for (int i = threadIdx.x; i < NB; i += 256)
            cnt[i * MS_BLOCKS + hb] = h[i];
    }
}

// ---------------- scan: per-chunk exclusive + single-block chunk-sum scan ----------------
__global__ __launch_bounds__(256) void scan_partial_g(
        const int* __restrict__ in, int* __restrict__ out,
        int* __restrict__ bsums, int n) {
    __shared__ int sd[256];
    int t = threadIdx.x;
    int base = blockIdx.x * GS_CHUNK;
    int i0 = base + 2 * t, i1 = i0 + 1;
    int d0 = (i0 < n) ? in[i0] : 0;
    int d1 = (i1 < n) ? in[i1] : 0;
    sd[t] = d0 + d1;
    __syncthreads();
    for (int o = 1; o < 256; o <<= 1) {
        int v = (t >= o) ? sd[t - o] : 0;
        __syncthreads();
        sd[t] += v;
        __syncthreads();
    }
    int excl = sd[t] - (d0 + d1);
    if (i0 < n) out[i0] = excl;
    if (i1 < n) out[i1] = excl + d0;
    if (t == 255) bsums[blockIdx.x] = sd[255];
}

// single-block scan of up to 1024 block-sums (4 per thread)
__global__ __launch_bounds__(256) void scan_bsums_kernel(int* __restrict__ bsums, int nb) {
    __shared__ int sd[256];
    int t = threadIdx.x;
    int v[4]; int s = 0;
#pragma unroll
    for (int k = 0; k < 4; ++k) {
        int i = t * 4 + k;
        v[k] = (i < nb) ? bsums[i] : 0;
        s += v[k];
    }
    sd[t] = s;
    __syncthreads();
    for (int o = 1; o < 256; o <<= 1) {
        int u = (t >= o) ? sd[t - o] : 0;
        __syncthreads();
        sd[t] += u;
        __syncthreads();
    }
    int run = sd[t] - s;
#pragma unroll
    for (int k = 0; k < 4; ++k) {
        int i = t * 4 + k;
        if (i < nb) bsums[i] = run;
        run += v[k];
    }
}

// ---------------- multi-split phase B: scatter packed (src<<8|dlocal) ----------------
// psum is the pre-addback scan; bsums folded in on the fly.
__global__ __launch_bounds__(256) void msplit_scatter_kernel(
        const int* __restrict__ src, const int* __restrict__ dst,
        const int* __restrict__ psum, const int* __restrict__ bsums,
        int* __restrict__ bucketed) {
    __shared__ int cur[NB];
    for (int i = threadIdx.x; i < NB; i += 256) {
        int idx = i * MS_BLOCKS + blockIdx.x;
        cur[i] = psum[idx] + bsums[idx >> 9];
    }
    __syncthreads();
    const int e0 = blockIdx.x * MS_EPB;
    for (int e = e0 + threadIdx.x; e < e0 + MS_EPB; e += 256) {
        int d = dst[e];
        int p = atomicAdd(&cur[d >> 8], 1);
        bucketed[p] = (src[e] << 8) | (d & 255);
    }
}

// ---------------- per-bucket local CSR (256-node buckets) ----------------
__global__ __launch_bounds__(256) void bucket_csr_kernel(
        const int* __restrict__ bucketed, const int* __restrict__ psum,
        const int* __restrict__ bsums,
        int* __restrict__ off, int* __restrict__ eidx) {
    const int j = blockIdx.x;
    const int t = threadIdx.x;
    __shared__ int deg[256];
    __shared__ int sd[256];
    __shared__ int base_s, size_s;
    if (t == 0) {
        int i0 = j * MS_BLOCKS;
        int b = psum[i0] + bsums[i0 >> 9];
        int nxt;
        if (j == NB - 1) nxt = N_EDGES;
        else {
            int i1 = (j + 1) * MS_BLOCKS;
            nxt = psum[i1] + bsums[i1 >> 9];
        }
        base_s = b; size_s = nxt - b;
    }
    deg[t] = 0;
    __syncthreads();
    const int base = base_s, size = size_s;
    const int nlo = j << 8;
    for (int i = t; i < size; i += 256)
        atomicAdd(&deg[(unsigned)bucketed[base + i] & 255u], 1);
    __syncthreads();
    int d0 = deg[t];
    sd[t] = d0;
    __syncthreads();
    for (int o = 1; o < 256; o <<= 1) {
        int v = (t >= o) ? sd[t - o] : 0;
        __syncthreads();
        sd[t] += v;
        __syncthreads();
    }
    int excl = sd[t] - d0;
    int g0 = nlo + t;
    if (g0 <= N_NODES) off[g0] = base + excl;
    __syncthreads();
    deg[t] = excl;
    __syncthreads();
    for (int i = t; i < size; i += 256) {
        unsigned e = (unsigned)bucketed[base + i];
        int p = atomicAdd(&deg[e & 255u], 1);
        eidx[base + p] = (int)(e >> 8);
    }
}

// ---------------- FUSED gather + MFMA GEMM1 + per-wave BN partials ----------------
// Barrier-free: each wave owns 16 consecutive nodes. 8-lane group g gathers
// nodes r0+2g, r0+2g+1 into the wave's private LDS slice (wave-local DS is
// in-order), the wave then ds_reads its A-fragments and runs its own MFMA.
// BN partials reduced across lhi groups via shfl_xor, one row per wave.
__global__ __launch_bounds__(256) void gather_gemm1_kernel(
        const unsigned short* __restrict__ xb, const int* __restrict__ off,
        const int* __restrict__ eidx, const unsigned short* __restrict__ W1t,
        const float* __restrict__ bias, unsigned short* __restrict__ hb,
        float* __restrict__ stats_partial) {
    __shared__ unsigned short agg[4][16 * LDS_STRIDE];
    const int lane = threadIdx.x & 63;
    const int g    = lane >> 3;
    const int col  = (lane & 7) << 3;
    const int w    = threadIdx.x >> 6;
    const int r0   = blockIdx.x * 64 + w * 16;
    const int wid  = blockIdx.x * 4 + w;
    const bool active = r0 < N_NODES;   // N_NODES % 16 == 0 -> whole tile valid

    float ssum[4] = {0.f, 0.f, 0.f, 0.f}, ssq[4] = {0.f, 0.f, 0.f, 0.f};

    if (active) {
        // ---- gather: 2 nodes per 8-lane group, into wave-private LDS ----
#pragma unroll
        for (int t = 0; t < 2; ++t) {
            const int n = r0 + 2 * g + t;
            const int beg = off[n], end = off[n + 1];
            bf16x8 s8 = *reinterpret_cast<const bf16x8*>(xb + (size_t)n * HID + col);
            float acc[8];
#pragma unroll
            for (int i = 0; i < 8; ++i) acc[i] = (float)s8[i];   // (1+eps)*x self
            int j = beg;
            for (; j + 8 <= end; j += 8) {
                int s0 = eidx[j],     s1 = eidx[j + 1], s2 = eidx[j + 2], s3 = eidx[j + 3];
                int s4 = eidx[j + 4], s5 = eidx[j + 5], s6 = eidx[j + 6], s7 = eidx[j + 7];
                bf16x8 r0v = *reinterpret_cast<const bf16x8*>(xb + (size_t)s0 * HID + col);
                bf16x8 r1v = *reinterpret_cast<const bf16x8*>(xb + (size_t)s1 * HID + col);
                bf16x8 r2v = *reinterpret_cast<const bf16x8*>(xb + (size_t)s2 * HID + col);
                bf16x8 r3v = *reinterpret_cast<const bf16x8*>(xb + (size_t)s3 * HID + col);
                bf16x8 r4v = *reinterpret_cast<const bf16x8*>(xb + (size_t)s4 * HID + col);
                bf16x8 r5v = *reinterpret_cast<const bf16x8*>(xb + (size_t)s5 * HID + col);
                bf16x8 r6v = *reinterpret_cast<const bf16x8*>(xb + (size_t)s6 * HID + col);
                bf16x8 r7v = *reinterpret_cast<const bf16x8*>(xb + (size_t)s7 * HID + col);
#pragma unroll
                for (int i = 0; i < 8; ++i)
                    acc[i] += (((float)r0v[i] + (float)r1v[i]) + ((float)r2v[i] + (float)r3v[i]))
                            + (((float)r4v[i] + (float)r5v[i]) + ((float)r6v[i] + (float)r7v[i]));
            }
            if (j + 4 <= end) {
                int s0 = eidx[j], s1 = eidx[j + 1], s2 = eidx[j + 2], s3 = eidx[j + 3];
                bf16x8 r0v = *reinterpret_cast<const bf16x8*>(xb + (size_t)s0 * HID + col);
                bf16x8 r1v = *reinterpret_cast<const bf16x8*>(xb + (size_t)s1 * HID + col);
                bf16x8 r2v = *reinterpret_cast<const bf16x8*>(xb + (size_t)s2 * HID + col);
                bf16x8 r3v = *reinterpret_cast<const bf16x8*>(xb + (size_t)s3 * HID + col);
#pragma unroll
                for (int i = 0; i < 8; ++i)
                    acc[i] += ((float)r0v[i] + (float)r1v[i]) + ((float)r2v[i] + (float)r3v[i]);
                j += 4;
            }
            for (; j < end; ++j) {
                int s0 = eidx[j];
                bf16x8 r0v = *reinterpret_cast<const bf16x8*>(xb + (size_t)s0 * HID + col);
#pragma unroll
                for (int i = 0; i < 8; ++i) acc[i] += (float)r0v[i];
            }
            u16x8 o;
#pragma unroll
            for (int i = 0; i < 8; ++i) o[i] = f2bf_rne(acc[i]);
            *reinterpret_cast<u16x8*>(&agg[w][(2 * g + t) * LDS_STRIDE + col]) = o;
        }

        // ---- MFMA on this wave's 16-row tile (wave-local LDS, no barrier) ----
        const int l15 = lane & 15, lhi = lane >> 4;
        bf16x8 bfrag[2][4];
        float bs[4];
#pragma unroll
        for (int f = 0; f < 4; ++f) {
            const unsigned short* wp = W1t + (size_t)(f * 16 + l15) * 64 + lhi * 8;
            bfrag[0][f] = *reinterpret_cast<const bf16x8*>(wp);
            bfrag[1][f] = *reinterpret_cast<const bf16x8*>(wp + 32);
            bs[f] = bias[f * 16 + l15];
        }
        const unsigned short* ap = &agg[w][l15 * LDS_STRIDE + lhi * 8];
        bf16x8 a0 = *reinterpret_cast<const bf16x8*>(ap);
        bf16x8 a1 = *reinterpret_cast<const bf16x8*>(ap + 32);
        f32x4 acc[4];
#pragma unroll
        for (int f = 0; f < 4; ++f) acc[f] = (f32x4){bs[f], bs[f], bs[f], bs[f]};
#pragma unroll
        for (int f = 0; f < 4; ++f) {
            acc[f] = __builtin_amdgcn_mfma_f32_16x16x32_bf16(a0, bfrag[0][f], acc[f], 0, 0, 0);
            acc[f] = __builtin_amdgcn_mfma_f32_16x16x32_bf16(a1, bfrag[1][f], acc[f], 0, 0, 0);
        }
#pragma unroll
        for (int f = 0; f < 4; ++f)
#pragma unroll
            for (int i = 0; i < 4; ++i) {
                hb[(size_t)(r0 + lhi * 4 + i) * 64 + f * 16 + l15] = f2bf_rne(acc[f][i]);
                ssum[f] += acc[f][i];
                ssq[f]  += acc[f][i] * acc[f][i];
            }
    }

    // ---- per-wave stats row: reduce across lhi groups via shfl ----
#pragma unroll
    for (int f = 0; f < 4; ++f) {
        ssum[f] += __shfl_xor(ssum[f], 16, 64);
        ssum[f] += __shfl_xor(ssum[f], 32, 64);
        ssq[f]  += __shfl_xor(ssq[f], 16, 64);
        ssq[f]  += __shfl_xor(ssq[f], 32, 64);
    }
    if (lane < 16) {
#pragma unroll
        for (int f = 0; f < 4; ++f) {
            stats_partial[(size_t)wid * 128 + f * 16 + lane]      = ssum[f];
            stats_partial[(size_t)wid * 128 + 64 + f * 16 + lane] = ssq[f];
        }
    }
}

// ---------------- stage 1: STAT_ROWS partial rows -> SR_BLOCKS rows ----------------
__global__ __launch_bounds__(256) void stats_reduce_kernel(
        const float* __restrict__ in, float* __restrict__ out, int nrows) {
    __shared__ float red[256];
    const int c = threadIdx.x & 127;
    const int half = threadIdx.x >> 7;   // 0 or 1
    float s = 0.f;
    for (int r = blockIdx.x + half * SR_BLOCKS; r < nrows; r += 2 * SR_BLOCKS)
        s += in[(size_t)r * 128 + c];
    red[threadIdx.x] = s;
    __syncthreads();
    if (half == 0)
        out[(size_t)blockIdx.x * 128 + c] = red[c] + red[128 + c];
}

// ---------------- MFMA: BN-apply + ReLU + GEMM2 + ReLU -> bf16 (layer 0) ----------------
__global__ __launch_bounds__(256) void bn_gemm_mfma_kernel(
        const unsigned short* __restrict__ hb, const unsigned short* __restrict__ W2t,
        const float* __restrict__ bias, const float* __restrict__ scale,
        const float* __restrict__ shift, unsigned short* __restrict__ outb) {
    const int lane = threadIdx.x & 63;
    const int l15 = lane & 15, lhi = lane >> 4;
    const int w = threadIdx.x >> 6;

    bf16x8 bfrag[2][4];
    float bs[4];
#pragma unroll
    for (int f = 0; f < 4; ++f) {
        const unsigned short* wp = W2t + (size_t)(f * 16 + l15) * 64 + lhi * 8;
        bfrag[0][f] = *reinterpret_cast<const bf16x8*>(wp);
        bfrag[1][f] = *reinterpret_cast<const bf16x8*>(wp + 32);
        bs[f] = bias[f * 16 + l15];
    }
    float sc[2][8], sh[2][8];
#pragma unroll
    for (int t = 0; t < 2; ++t)
#pragma unroll
        for (int j = 0; j < 8; ++j) {
            int k = t * 32 + lhi * 8 + j;
            sc[t][j] = scale[k];
            sh[t][j] = shift[k];
        }

    const int tile0 = (blockIdx.x * 4 + w) * TPW2;
#pragma unroll
    for (int tt = 0; tt < TPW2; ++tt) {
        const int tile = tile0 + tt;
        if (tile >= ROW_TILES) return;
        const int r0 = tile * 16;
        f32x4 acc[4];
#pragma unroll
        for (int f = 0; f < 4; ++f) acc[f] = (f32x4){bs[f], bs[f], bs[f], bs[f]};
#pragma unroll
        for (int t = 0; t < 2; ++t) {
            const unsigned short* hp = hb + (size_t)(r0 + l15) * 64 + t * 32 + lhi * 8;
            bf16x8 raw = *reinterpret_cast<const bf16x8*>(hp);
            bf16x8 a;
#pragma unroll
            for (int j = 0; j < 8; ++j)
                a[j] = (__bf16)fmaxf(fmaf(sc[t][j], (float)raw[j], sh[t][j]), 0.f);
#pragma unroll
            for (int f = 0; f < 4; ++f)
                acc[f] = __builtin_amdgcn_mfma_f32_16x16x32_bf16(a, bfrag[t][f], acc[f], 0, 0, 0);
        }
#pragma unroll
        for (int f = 0; f < 4; ++f)
#pragma unroll
            for (int i = 0; i < 4; ++i)
                outb[(size_t)(r0 + lhi * 4 + i) * 64 + f * 16 + l15] =
                    f2bf_rne(fmaxf(acc[f][i], 0.f));
    }
}

// ---------------- FUSED layer-1 BN+GEMM2+ReLU -> (LDS transpose) -> jump head ----------------
#define LT_STRIDE 88
__global__ __launch_bounds__(256) void bn_gemm_jumphead_kernel(
        const unsigned short* __restrict__ hb, const unsigned short* __restrict__ W2t,
        const float* __restrict__ bias2, const float* __restrict__ scale,
        const float* __restrict__ shift,
        const unsigned short* __restrict__ xb, const unsigned short* __restrict__ h1b,
        const unsigned short* __restrict__ Wt, const float* __restrict__ bjk,
        float* __restrict__ out) {
    __shared__ unsigned short lt[4][16 * LT_STRIDE];
    const int lane = threadIdx.x & 63;
    const int l15 = lane & 15, lhi = lane >> 4;
    const int w = threadIdx.x >> 6;

    bf16x8 b2frag[2][4];
    float bs2[4];
#pragma unroll
    for (int f = 0; f < 4; ++f) {
        const unsigned short* wp = W2t + (size_t)(f * 16 + l15) * 64 + lhi * 8;
        b2frag[0][f] = *reinterpret_cast<const bf16x8*>(wp);
        b2frag[1][f] = *reinterpret_cast<const bf16x8*>(wp + 32);
        bs2[f] = bias2[f * 16 + l15];
    }
    float sc[2][8], sh[2][8];
#pragma unroll
    for (int t = 0; t < 2; ++t)
#pragma unroll
        for (int j = 0; j < 8; ++j) {
            int k = t * 32 + lhi * 8 + j;
            sc[t][j] = scale[k];
            sh[t][j] = shift[k];
        }
    bf16x8 bjfrag[6][4];
    float bsj[4];
#pragma unroll
    for (int f = 0; f < 4; ++f) {
        const unsigned short* wp = Wt + (size_t)(f * 16 + l15) * 192 + lhi * 8;
#pragma unroll
        for (int t = 0; t < 6; ++t)
            bjfrag[t][f] = *reinterpret_cast<const bf16x8*>(wp + t * 32);
        bsj[f] = bjk[f * 16 + l15];
    }

    const int tile0 = (blockIdx.x * 4 + w) * TPW2;
#pragma unroll
    for (int tt = 0; tt < TPW2; ++tt) {
        const int tile = tile0 + tt;
        if (tile >= ROW_TILES) return;
        const int r0 = tile * 16;

        f32x4 acc2[4];
#pragma unroll
        for (int f = 0; f < 4; ++f) acc2[f] = (f32x4){bs2[f], bs2[f], bs2[f], bs2[f]};
#pragma unroll
        for (int t = 0; t < 2; ++t) {
            const unsigned short* hp = hb + (size_t)(r0 + l15) * 64 + t * 32 + lhi * 8;
            bf16x8 raw = *reinterpret_cast<const bf16x8*>(hp);
            bf16x8 a;
#pragma unroll
            for (int j = 0; j < 8; ++j)
                a[j] = (__bf16)fmaxf(fmaf(sc[t][j], (float)raw[j], sh[t][j]), 0.f);
#pragma unroll
            for (int f = 0; f < 4; ++f)
                acc2[f] = __builtin_amdgcn_mfma_f32_16x16x32_bf16(a, b2frag[t][f], acc2[f], 0, 0, 0);
        }
#pragma unroll
        for (int f = 0; f < 4; ++f)
#pragma unroll
            for (int i = 0; i < 4; ++i)
                lt[w][(lhi * 4 + i) * LT_STRIDE + f * 16 + l15] =
                    f2bf_rne(fmaxf(acc2[f][i], 0.f));
        bf16x8 a4 = *reinterpret_cast<const bf16x8*>(&lt[w][l15 * LT_STRIDE + lhi * 8]);
        bf16x8 a5 = *reinterpret_cast<const bf16x8*>(&lt[w][l15 * LT_STRIDE + 32 + lhi * 8]);

        const size_t arow = (size_t)(r0 + l15) * 64 + lhi * 8;
        bf16x8 a0 = *reinterpret_cast<const bf16x8*>(xb + arow);
        bf16x8 a1 = *reinterpret_cast<const bf16x8*>(xb + arow + 32);
        bf16x8 a2 = *reinterpret_cast<const bf16x8*>(h1b + arow);
        bf16x8 a3 = *reinterpret_cast<const bf16x8*>(h1b + arow + 32);
        f32x4 accj[4];
#pragma unroll
        for (int f = 0; f < 4; ++f) accj[f] = (f32x4){bsj[f], bsj[f], bsj[f], bsj[f]};
#pragma unroll
        for (int f = 0; f < 4; ++f) {
            accj[f] = __builtin_amdgcn_mfma_f32_16x16x32_bf16(a0, bjfrag[0][f], accj[f], 0, 0, 0);
            accj[f] = __builtin_amdgcn_mfma_f32_16x16x32_bf16(a1, bjfrag[1][f], accj[f], 0, 0, 0);
            accj[f] = __builtin_amdgcn_mfma_f32_16x16x32_bf16(a2, bjfrag[2][f], accj[f], 0, 0, 0);
            accj[f] = __builtin_amdgcn_mfma_f32_16x16x32_bf16(a3, bjfrag[3][f], accj[f], 0, 0, 0);
            accj[f] = __builtin_amdgcn_mfma_f32_16x16x32_bf16(a4, bjfrag[4][f], accj[f], 0, 0, 0);
            accj[f] = __builtin_amdgcn_mfma_f32_16x16x32_bf16(a5, bjfrag[5][f], accj[f], 0, 0, 0);
        }
#pragma unroll
        for (int f = 0; f < 4; ++f)
#pragma unroll
            for (int i = 0; i < 4; ++i)
                out[(size_t)(r0 + lhi * 4 + i) * 64 + f * 16 + l15] = accj[f][i];
    }
}

// ---------------- BN finalize: reduce SR_BLOCKS rows -> scale/shift ----------------
__global__ __launch_bounds__(1024) void bn_finalize_kernel(
        const float* __restrict__ stats_partial, int nblocks,
        const float* __restrict__ gamma, const float* __restrict__ beta,
        float* __restrict__ scale, float* __restrict__ shift) {
    __shared__ float red[2][1024];
    const int t = threadIdx.x;
    const int c = t & 63;
    const int chunk = t >> 6;        // 0..15
    float s = 0.f, q = 0.f;
    for (int b = chunk; b < nblocks; b += 16) {
        s += stats_partial[(size_t)b * 128 + c];
        q += stats_partial[(size_t)b * 128 + 64 + c];
    }
    red[0][t] = s;
    red[1][t] = q;
    __syncthreads();
    if (chunk == 0) {
        float ss = 0.f, qq = 0.f;
#pragma unroll
        for (int k = 0; k < 16; ++k) {
            ss += red[0][k * 64 + c];
            qq += red[1][k * 64 + c];
        }
        float mean = ss / (float)N_NODES;
        float var  = qq / (float)N_NODES - mean * mean;
        float scl  = gamma[c] * rsqrtf(var + BN_EPS);
        scale[c] = scl;
        shift[c] = beta[c] - mean * scl;
    }
}

extern "C" void kernel_launch(void* const* d_in, const int* in_sizes, int n_in,
                              void* d_out, int out_size, void* d_ws, size_t ws_size,
                              hipStream_t stream) {
    const float* x    = (const float*)d_in[0];
    const int*   ei   = (const int*)d_in[1];
    const int*   src  = ei;
    const int*   dst  = ei + N_EDGES;
    const float* W1_0 = (const float*)d_in[3];
    const float* b1_0 = (const float*)d_in[4];
    const float* g_0  = (const float*)d_in[5];
    const float* be_0 = (const float*)d_in[6];
    const float* W2_0 = (const float*)d_in[7];
    const float* b2_0 = (const float*)d_in[8];
    const float* W1_1 = (const float*)d_in[9];
    const float* b1_1 = (const float*)d_in[10];
    const float* g_1  = (const float*)d_in[11];
    const float* be_1 = (const float*)d_in[12];
    const float* W2_1 = (const float*)d_in[13];
    const float* b2_1 = (const float*)d_in[14];
    const float* Wjk  = (const float*)d_in[15];
    const float* bjk  = (const float*)d_in[16];

    const size_t FEAT = (size_t)N_NODES * HID;

    unsigned short* hb   = (unsigned short*)d_ws;          // FEAT bf16
    unsigned short* xb   = hb + FEAT;                      // FEAT bf16
    unsigned short* h1b  = xb + FEAT;                      // FEAT bf16
    int*   bucketed = (int*)(h1b + FEAT);                  // N_EDGES
    float* stats  = (float*)(bucketed + N_EDGES);          // STAT_ROWS * 128
    float* stats2 = stats + (size_t)STAT_ROWS * 128;       // SR_BLOCKS * 128
    float* scale  = stats2 + (size_t)SR_BLOCKS * 128;
    float* shift  = scale + 64;
    int*   off   = (int*)(shift + 64);                     // N_NODES + 1 (pad 2)
    int*   eidx  = off + N_NODES + 2;                      // N_EDGES
    int*   cnt   = eidx + N_EDGES;                         // MS_CNT
    int*   psum  = cnt + MS_CNT;                           // MS_CNT (pad 2)
    int*   bsums = psum + MS_CNT + 2;                      // 1024
    unsigned short* wjk_t = (unsigned short*)(bsums + 1024);// 64*192
    unsigned short* w2t_0 = wjk_t + 64 * 192;              // 64*64
    unsigned short* w2t_1 = w2t_0 + 64 * 64;               // 64*64
    unsigned short* w1t_0 = w2t_1 + 64 * 64;               // 64*64
    unsigned short* w1t_1 = w1t_0 + 64 * 64;               // 64*64
    float* out   = (float*)d_out;

    // ---------------- prep: cvt + wtrans + hist in one launch ----------------
    prep_kernel<<<PREP_BLOCKS, 256, 0, stream>>>(
        x, xb, Wjk, W1_0, W2_0, W1_1, W2_1,
        wjk_t, w1t_0, w2t_0, w1t_1, w2t_1, dst, cnt);

    // ---------------- CSR build (addback folded into consumers) ----------------
    scan_partial_g<<<GS_BLOCKS, 256, 0, stream>>>(cnt, psum, bsums, MS_CNT);
    scan_bsums_kernel<<<1, 256, 0, stream>>>(bsums, GS_BLOCKS);
    msplit_scatter_kernel<<<MS_BLOCKS, 256, 0, stream>>>(src, dst, psum, bsums, bucketed);
    bucket_csr_kernel<<<NB, 256, 0, stream>>>(bucketed, psum, bsums, off, eidx);

    // ---------------- layer 0 ----------------
    gather_gemm1_kernel<<<GG_BLOCKS, 256, 0, stream>>>(
        xb, off, eidx, w1t_0, b1_0, hb, stats);
    stats_reduce_kernel<<<SR_BLOCKS, 256, 0, stream>>>(stats, stats2, STAT_ROWS);
    bn_finalize_kernel<<<1, 1024, 0, stream>>>(stats2, SR_BLOCKS, g_0, be_0, scale, shift);
    bn_gemm_mfma_kernel<<<G2_BLOCKS, 256, 0, stream>>>(hb, w2t_0, b2_0, scale, shift, h1b);

    // ---------------- layer 1 (GEMM2 fused into jump head) ----------------
    gather_gemm1_kernel<<<GG_BLOCKS, 256, 0, stream>>>(
        h1b, off, eidx, w1t_1, b1_1, hb, stats);
    stats_reduce_kernel<<<SR_BLOCKS, 256, 0, stream>>>(stats, stats2, STAT_ROWS);
    bn_finalize_kernel<<<1, 1024, 0, stream>>>(stats2, SR_BLOCKS, g_1, be_1, scale, shift);
    bn_gemm_jumphead_kernel<<<G2_BLOCKS, 256, 0, stream>>>(
        hb, w2t_1, b2_1, scale, shift, xb, h1b, wjk_t, bjk, out);
}

// Round 16
// 182.673 us; speedup vs baseline: 1.1296x; 1.1296x over previous
//
#include <hip/hip_runtime.h>

#define N_NODES 100000
#define N_EDGES 1600000
#define HID 64
#define BN_EPS 1e-5f

// ---- gather: 8 nodes/wave, 32 nodes/block ----
#define GATHER_BLOCKS (N_NODES / 32)                 // 3125 (exact)

// ---- MFMA tiling: 16-row tiles ----
#define ROW_TILES (N_NODES / 16)                     // 6250 (exact)
#define TPW1 4                                       // tiles/wave, gemm1
#define G1_BLOCKS ((ROW_TILES + 4*TPW1 - 1) / (4*TPW1))   // 391
#define TPW2 2                                       // tiles/wave, bn_gemm & fused jk
#define G2_BLOCKS ((ROW_TILES + 4*TPW2 - 1) / (4*TPW2))   // 782

// ---- stats two-stage reduction ----
#define SR_BLOCKS 64

// ---- multi-split CSR build parameters ----
#define NB 391                              // coarse buckets of 256 nodes (dst>>8)
#define MS_BLOCKS 1000
#define MS_EPB (N_EDGES / MS_BLOCKS)        // 1600 edges per block
#define MS_CNT (NB * MS_BLOCKS)             // 391000 segment counters
#define GS_CHUNK 512
#define GS_BLOCKS ((MS_CNT + GS_CHUNK - 1) / GS_CHUNK)   // 764

// ---- prep kernel block ranges ----
#define CVT_B 3125                          // FEAT/8/256
#define WT_B 112                            // (12288+16384)/256
#define PREP_BLOCKS (CVT_B + WT_B + MS_BLOCKS)

typedef __bf16 bf16x8 __attribute__((ext_vector_type(8)));
typedef float  f32x4  __attribute__((ext_vector_type(4)));
typedef unsigned short u16x8 __attribute__((ext_vector_type(8)));

__device__ __forceinline__ float bf2f(unsigned short u) {
    return __uint_as_float(((unsigned)u) << 16);
}
__device__ __forceinline__ unsigned short f2bf_rne(float f) {
    unsigned u = __float_as_uint(f);
    u += 0x7FFFu + ((u >> 16) & 1u);
    return (unsigned short)(u >> 16);
}

// ---------------- prep: x->bf16 cvt + weight transposes + msplit hist ----------------
__global__ __launch_bounds__(256) void prep_kernel(
        const float* __restrict__ x, unsigned short* __restrict__ xb,
        const float* __restrict__ Wjk,
        const float* __restrict__ W1_0, const float* __restrict__ W2_0,
        const float* __restrict__ W1_1, const float* __restrict__ W2_1,
        unsigned short* __restrict__ wjk_t,
        unsigned short* __restrict__ w1t_0, unsigned short* __restrict__ w2t_0,
        unsigned short* __restrict__ w1t_1, unsigned short* __restrict__ w2t_1,
        const int* __restrict__ dst, int* __restrict__ cnt) {
    __shared__ int h[NB];
    const int b = blockIdx.x;
    if (b < CVT_B) {
        size_t i = ((size_t)b * 256 + threadIdx.x) * 8;
        float4 a = *reinterpret_cast<const float4*>(x + i);
        float4 c = *reinterpret_cast<const float4*>(x + i + 4);
        ushort4 w0 = make_ushort4(f2bf_rne(a.x), f2bf_rne(a.y), f2bf_rne(a.z), f2bf_rne(a.w));
        ushort4 w1 = make_ushort4(f2bf_rne(c.x), f2bf_rne(c.y), f2bf_rne(c.z), f2bf_rne(c.w));
        *reinterpret_cast<ushort4*>(xb + i) = w0;
        *reinterpret_cast<ushort4*>(xb + i + 4) = w1;
    } else if (b < CVT_B + WT_B) {
        int i = (b - CVT_B) * 256 + threadIdx.x;
        if (i < 12288) {
            int c = i / 192, k = i - c * 192;
            wjk_t[i] = f2bf_rne(Wjk[k * 64 + c]);
        } else {
            int r = i - 12288;
            int which = r >> 12, rem = r & 4095;
            int c = rem >> 6, k = rem & 63;
            const float* W = (which == 0) ? W1_0 : (which == 1) ? W2_0
                           : (which == 2) ? W1_1 : W2_1;
            unsigned short* Wt = (which == 0) ? w1t_0 : (which == 1) ? w2t_0
                               : (which == 2) ? w1t_1 : w2t_1;
            Wt[rem] = f2bf_rne(W[k * 64 + c]);
        }
    } else {
        const int hb = b - CVT_B - WT_B;
        for (int i = threadIdx.x; i < NB; i += 256) h[i] = 0;
        __syncthreads();
        const int e0 = hb * MS_EPB;
        for (int e = e0 + threadIdx.x; e < e0 + MS_EPB; e += 256)
            atomicAdd(&h[dst[e] >> 8], 1);
        __syncthreads();
        for (int i = threadIdx.x; i < NB; i += 256)
            cnt[i * MS_BLOCKS + hb] = h[i];
    }
}

// ---------------- scan: per-chunk exclusive + single-block chunk-sum scan ----------------
__global__ __launch_bounds__(256) void scan_partial_g(
        const int* __restrict__ in, int* __restrict__ out,
        int* __restrict__ bsums, int n) {
    __shared__ int sd[256];
    int t = threadIdx.x;
    int base = blockIdx.x * GS_CHUNK;
    int i0 = base + 2 * t, i1 = i0 + 1;
    int d0 = (i0 < n) ? in[i0] : 0;
    int d1 = (i1 < n) ? in[i1] : 0;
    sd[t] = d0 + d1;
    __syncthreads();
    for (int o = 1; o < 256; o <<= 1) {
        int v = (t >= o) ? sd[t - o] : 0;
        __syncthreads();
        sd[t] += v;
        __syncthreads();
    }
    int excl = sd[t] - (d0 + d1);
    if (i0 < n) out[i0] = excl;
    if (i1 < n) out[i1] = excl + d0;
    if (t == 255) bsums[blockIdx.x] = sd[255];
}

// single-block scan of up to 1024 block-sums (4 per thread)
__global__ __launch_bounds__(256) void scan_bsums_kernel(int* __restrict__ bsums, int nb) {
    __shared__ int sd[256];
    int t = threadIdx.x;
    int v[4]; int s = 0;
#pragma unroll
    for (int k = 0; k < 4; ++k) {
        int i = t * 4 + k;
        v[k] = (i < nb) ? bsums[i] : 0;
        s += v[k];
    }
    sd[t] = s;
    __syncthreads();
    for (int o = 1; o < 256; o <<= 1) {
        int u = (t >= o) ? sd[t - o] : 0;
        __syncthreads();
        sd[t] += u;
        __syncthreads();
    }
    int run = sd[t] - s;
#pragma unroll
    for (int k = 0; k < 4; ++k) {
        int i = t * 4 + k;
        if (i < nb) bsums[i] = run;
        run += v[k];
    }
}

// ---------------- multi-split phase B: scatter packed (src<<8|dlocal) ----------------
// psum is the pre-addback scan; bsums folded in on the fly.
__global__ __launch_bounds__(256) void msplit_scatter_kernel(
        const int* __restrict__ src, const int* __restrict__ dst,
        const int* __restrict__ psum, const int* __restrict__ bsums,
        int* __restrict__ bucketed) {
    __shared__ int cur[NB];
    for (int i = threadIdx.x; i < NB; i += 256) {
        int idx = i * MS_BLOCKS + blockIdx.x;
        cur[i] = psum[idx] + bsums[idx >> 9];
    }
    __syncthreads();
    const int e0 = blockIdx.x * MS_EPB;
    for (int e = e0 + threadIdx.x; e < e0 + MS_EPB; e += 256) {
        int d = dst[e];
        int p = atomicAdd(&cur[d >> 8], 1);
        bucketed[p] = (src[e] << 8) | (d & 255);
    }
}

// ---------------- per-bucket local CSR (256-node buckets) ----------------
__global__ __launch_bounds__(256) void bucket_csr_kernel(
        const int* __restrict__ bucketed, const int* __restrict__ psum,
        const int* __restrict__ bsums,
        int* __restrict__ off, int* __restrict__ eidx) {
    const int j = blockIdx.x;
    const int t = threadIdx.x;
    __shared__ int deg[256];
    __shared__ int sd[256];
    __shared__ int base_s, size_s;
    if (t == 0) {
        int i0 = j * MS_BLOCKS;
        int b = psum[i0] + bsums[i0 >> 9];
        int nxt;
        if (j == NB - 1) nxt = N_EDGES;
        else {
            int i1 = (j + 1) * MS_BLOCKS;
            nxt = psum[i1] + bsums[i1 >> 9];
        }
        base_s = b; size_s = nxt - b;
    }
    deg[t] = 0;
    __syncthreads();
    const int base = base_s, size = size_s;
    const int nlo = j << 8;
    for (int i = t; i < size; i += 256)
        atomicAdd(&deg[(unsigned)bucketed[base + i] & 255u], 1);
    __syncthreads();
    int d0 = deg[t];
    sd[t] = d0;
    __syncthreads();
    for (int o = 1; o < 256; o <<= 1) {
        int v = (t >= o) ? sd[t - o] : 0;
        __syncthreads();
        sd[t] += v;
        __syncthreads();
    }
    int excl = sd[t] - d0;
    int g0 = nlo + t;
    if (g0 <= N_NODES) off[g0] = base + excl;
    __syncthreads();
    deg[t] = excl;
    __syncthreads();
    for (int i = t; i < size; i += 256) {
        unsigned e = (unsigned)bucketed[base + i];
        int p = atomicAdd(&deg[e & 255u], 1);
        eidx[base + p] = (int)(e >> 8);
    }
}

// ---------------- gather: 8 nodes per wave, lane-private accumulators ----------------
__global__ __launch_bounds__(256) void gather_kernel(
        const unsigned short* __restrict__ xb, const int* __restrict__ off,
        const int* __restrict__ eidx, unsigned short* __restrict__ aggb) {
    const int lane = threadIdx.x & 63;
    const int g    = lane >> 3;
    const int col  = (lane & 7) << 3;
    const int w    = threadIdx.x >> 6;
    const int n = blockIdx.x * 32 + w * 8 + g;

    const int beg = off[n], end = off[n + 1];
    bf16x8 s8 = *reinterpret_cast<const bf16x8*>(xb + (size_t)n * HID + col);
    float acc[8];
#pragma unroll
    for (int i = 0; i < 8; ++i) acc[i] = (float)s8[i];   // (1+eps)*x self, eps=0

    int j = beg;
    for (; j + 4 <= end; j += 4) {
        int s0 = eidx[j], s1 = eidx[j + 1], s2 = eidx[j + 2], s3 = eidx[j + 3];
        bf16x8 r0 = *reinterpret_cast<const bf16x8*>(xb + (size_t)s0 * HID + col);
        bf16x8 r1 = *reinterpret_cast<const bf16x8*>(xb + (size_t)s1 * HID + col);
        bf16x8 r2 = *reinterpret_cast<const bf16x8*>(xb + (size_t)s2 * HID + col);
        bf16x8 r3 = *reinterpret_cast<const bf16x8*>(xb + (size_t)s3 * HID + col);
#pragma unroll
        for (int i = 0; i < 8; ++i)
            acc[i] += ((float)r0[i] + (float)r1[i]) + ((float)r2[i] + (float)r3[i]);
    }
    for (; j < end; ++j) {
        int s0 = eidx[j];
        bf16x8 r0 = *reinterpret_cast<const bf16x8*>(xb + (size_t)s0 * HID + col);
#pragma unroll
        for (int i = 0; i < 8; ++i) acc[i] += (float)r0[i];
    }

    u16x8 o;
#pragma unroll
    for (int i = 0; i < 8; ++i) o[i] = f2bf_rne(acc[i]);
    *reinterpret_cast<u16x8*>(aggb + (size_t)n * HID + col) = o;
}

// ---------------- MFMA GEMM1: hb = aggb @ W1 + b1 (bf16 out) + BN partials ----------------
__global__ __launch_bounds__(256) void gemm1_mfma_kernel(
        const unsigned short* __restrict__ aggb, const unsigned short* __restrict__ W1t,
        const float* __restrict__ bias, unsigned short* __restrict__ hb,
        float* __restrict__ stats_partial) {
    const int lane = threadIdx.x & 63;
    const int l15 = lane & 15, lhi = lane >> 4;
    const int w = threadIdx.x >> 6;

    bf16x8 bfrag[2][4];
    float bs[4];
#pragma unroll
    for (int f = 0; f < 4; ++f) {
        const unsigned short* wp = W1t + (size_t)(f * 16 + l15) * 64 + lhi * 8;
        bfrag[0][f] = *reinterpret_cast<const bf16x8*>(wp);
        bfrag[1][f] = *reinterpret_cast<const bf16x8*>(wp + 32);
        bs[f] = bias[f * 16 + l15];
    }

    float ssum[4] = {0.f, 0.f, 0.f, 0.f}, ssq[4] = {0.f, 0.f, 0.f, 0.f};

    const int tile0 = (blockIdx.x * 4 + w) * TPW1;
#pragma unroll
    for (int tt = 0; tt < TPW1; ++tt) {
        const int tile = tile0 + tt;
        if (tile < ROW_TILES) {
            const int r0 = tile * 16;
            const size_t arow = (size_t)(r0 + l15) * 64 + lhi * 8;
            bf16x8 a0 = *reinterpret_cast<const bf16x8*>(aggb + arow);
            bf16x8 a1 = *reinterpret_cast<const bf16x8*>(aggb + arow + 32);
            f32x4 acc[4];
#pragma unroll
            for (int f = 0; f < 4; ++f) acc[f] = (f32x4){bs[f], bs[f], bs[f], bs[f]};
#pragma unroll
            for (int f = 0; f < 4; ++f) {
                acc[f] = __builtin_amdgcn_mfma_f32_16x16x32_bf16(a0, bfrag[0][f], acc[f], 0, 0, 0);
                acc[f] = __builtin_amdgcn_mfma_f32_16x16x32_bf16(a1, bfrag[1][f], acc[f], 0, 0, 0);
            }
#pragma unroll
            for (int f = 0; f < 4; ++f)
#pragma unroll
                for (int i = 0; i < 4; ++i) {
                    hb[(size_t)(r0 + lhi * 4 + i) * 64 + f * 16 + l15] = f2bf_rne(acc[f][i]);
                    ssum[f] += acc[f][i];
                    ssq[f]  += acc[f][i] * acc[f][i];
                }
        }
    }

    __shared__ float red[2][4][256];
#pragma unroll
    for (int f = 0; f < 4; ++f) {
        red[0][f][threadIdx.x] = ssum[f];
        red[1][f][threadIdx.x] = ssq[f];
    }
    __syncthreads();
    if (threadIdx.x < 64) {
        int c = threadIdx.x, f = c >> 4, p = c & 15;
        float s = 0.f, q = 0.f;
#pragma unroll
        for (int u = 0; u < 16; ++u) {
            int t = (u >> 2) * 64 + (u & 3) * 16 + p;
            s += red[0][f][t];
            q += red[1][f][t];
        }
        stats_partial[(size_t)blockIdx.x * 128 + c]      = s;
        stats_partial[(size_t)blockIdx.x * 128 + 64 + c] = q;
    }
}

// ---------------- stage 1: G1_BLOCKS partial rows -> SR_BLOCKS rows ----------------
__global__ __launch_bounds__(256) void stats_reduce_kernel(
        const float* __restrict__ in, float* __restrict__ out, int nrows) {
    __shared__ float red[256];
    const int c = threadIdx.x & 127;
    const int half = threadIdx.x >> 7;   // 0 or 1
    float s = 0.f;
    for (int r = blockIdx.x + half * SR_BLOCKS; r < nrows; r += 2 * SR_BLOCKS)
        s += in[(size_t)r * 128 + c];
    red[threadIdx.x] = s;
    __syncthreads();
    if (half == 0)
        out[(size_t)blockIdx.x * 128 + c] = red[c] + red[128 + c];
}

// ---------------- MFMA: BN-apply + ReLU + GEMM2 + ReLU -> bf16 (layer 0) ----------------
__global__ __launch_bounds__(256) void bn_gemm_mfma_kernel(
        const unsigned short* __restrict__ hb, const unsigned short* __restrict__ W2t,
        const float* __restrict__ bias, const float* __restrict__ scale,
        const float* __restrict__ shift, unsigned short* __restrict__ outb) {
    const int lane = threadIdx.x & 63;
    const int l15 = lane & 15, lhi = lane >> 4;
    const int w = threadIdx.x >> 6;

    bf16x8 bfrag[2][4];
    float bs[4];
#pragma unroll
    for (int f = 0; f < 4; ++f) {
        const unsigned short* wp = W2t + (size_t)(f * 16 + l15) * 64 + lhi * 8;
        bfrag[0][f] = *reinterpret_cast<const bf16x8*>(wp);
        bfrag[1][f] = *reinterpret_cast<const bf16x8*>(wp + 32);
        bs[f] = bias[f * 16 + l15];
    }
    float sc[2][8], sh[2][8];
#pragma unroll
    for (int t = 0; t < 2; ++t)
#pragma unroll
        for (int j = 0; j < 8; ++j) {
            int k = t * 32 + lhi * 8 + j;
            sc[t][j] = scale[k];
            sh[t][j] = shift[k];
        }

    const int tile0 = (blockIdx.x * 4 + w) * TPW2;
#pragma unroll
    for (int tt = 0; tt < TPW2; ++tt) {
        const int tile = tile0 + tt;
        if (tile >= ROW_TILES) return;
        const int r0 = tile * 16;
        f32x4 acc[4];
#pragma unroll
        for (int f = 0; f < 4; ++f) acc[f] = (f32x4){bs[f], bs[f], bs[f], bs[f]};
#pragma unroll
        for (int t = 0; t < 2; ++t) {
            const unsigned short* hp = hb + (size_t)(r0 + l15) * 64 + t * 32 + lhi * 8;
            bf16x8 raw = *reinterpret_cast<const bf16x8*>(hp);
            bf16x8 a;
#pragma unroll
            for (int j = 0; j < 8; ++j)
                a[j] = (__bf16)fmaxf(fmaf(sc[t][j], (float)raw[j], sh[t][j]), 0.f);
#pragma unroll
            for (int f = 0; f < 4; ++f)
                acc[f] = __builtin_amdgcn_mfma_f32_16x16x32_bf16(a, bfrag[t][f], acc[f], 0, 0, 0);
        }
#pragma unroll
        for (int f = 0; f < 4; ++f)
#pragma unroll
            for (int i = 0; i < 4; ++i)
                outb[(size_t)(r0 + lhi * 4 + i) * 64 + f * 16 + l15] =
                    f2bf_rne(fmaxf(acc[f][i], 0.f));
    }
}

// ---------------- FUSED layer-1 BN+GEMM2+ReLU -> (LDS transpose) -> jump head ----------------
#define LT_STRIDE 88
__global__ __launch_bounds__(256) void bn_gemm_jumphead_kernel(
        const unsigned short* __restrict__ hb, const unsigned short* __restrict__ W2t,
        const float* __restrict__ bias2, const float* __restrict__ scale,
        const float* __restrict__ shift,
        const unsigned short* __restrict__ xb, const unsigned short* __restrict__ h1b,
        const unsigned short* __restrict__ Wt, const float* __restrict__ bjk,
        float* __restrict__ out) {
    __shared__ unsigned short lt[4][16 * LT_STRIDE];
    const int lane = threadIdx.x & 63;
    const int l15 = lane & 15, lhi = lane >> 4;
    const int w = threadIdx.x >> 6;

    bf16x8 b2frag[2][4];
    float bs2[4];
#pragma unroll
    for (int f = 0; f < 4; ++f) {
        const unsigned short* wp = W2t + (size_t)(f * 16 + l15) * 64 + lhi * 8;
        b2frag[0][f] = *reinterpret_cast<const bf16x8*>(wp);
        b2frag[1][f] = *reinterpret_cast<const bf16x8*>(wp + 32);
        bs2[f] = bias2[f * 16 + l15];
    }
    float sc[2][8], sh[2][8];
#pragma unroll
    for (int t = 0; t < 2; ++t)
#pragma unroll
        for (int j = 0; j < 8; ++j) {
            int k = t * 32 + lhi * 8 + j;
            sc[t][j] = scale[k];
            sh[t][j] = shift[k];
        }
    bf16x8 bjfrag[6][4];
    float bsj[4];
#pragma unroll
    for (int f = 0; f < 4; ++f) {
        const unsigned short* wp = Wt + (size_t)(f * 16 + l15) * 192 + lhi * 8;
#pragma unroll
        for (int t = 0; t < 6; ++t)
            bjfrag[t][f] = *reinterpret_cast<const bf16x8*>(wp + t * 32);
        bsj[f] = bjk[f * 16 + l15];
    }

    const int tile0 = (blockIdx.x * 4 + w) * TPW2;
#pragma unroll
    for (int tt = 0; tt < TPW2; ++tt) {
        const int tile = tile0 + tt;
        if (tile >= ROW_TILES) return;
        const int r0 = tile * 16;

        f32x4 acc2[4];
#pragma unroll
        for (int f = 0; f < 4; ++f) acc2[f] = (f32x4){bs2[f], bs2[f], bs2[f], bs2[f]};
#pragma unroll
        for (int t = 0; t < 2; ++t) {
            const unsigned short* hp = hb + (size_t)(r0 + l15) * 64 + t * 32 + lhi * 8;
            bf16x8 raw = *reinterpret_cast<const bf16x8*>(hp);
            bf16x8 a;
#pragma unroll
            for (int j = 0; j < 8; ++j)
                a[j] = (__bf16)fmaxf(fmaf(sc[t][j], (float)raw[j], sh[t][j]), 0.f);
#pragma unroll
            for (int f = 0; f < 4; ++f)
                acc2[f] = __builtin_amdgcn_mfma_f32_16x16x32_bf16(a, b2frag[t][f], acc2[f], 0, 0, 0);
        }
#pragma unroll
        for (int f = 0; f < 4; ++f)
#pragma unroll
            for (int i = 0; i < 4; ++i)
                lt[w][(lhi * 4 + i) * LT_STRIDE + f * 16 + l15] =
                    f2bf_rne(fmaxf(acc2[f][i], 0.f));
        bf16x8 a4 = *reinterpret_cast<const bf16x8*>(&lt[w][l15 * LT_STRIDE + lhi * 8]);
        bf16x8 a5 = *reinterpret_cast<const bf16x8*>(&lt[w][l15 * LT_STRIDE + 32 + lhi * 8]);

        const size_t arow = (size_t)(r0 + l15) * 64 + lhi * 8;
        bf16x8 a0 = *reinterpret_cast<const bf16x8*>(xb + arow);
        bf16x8 a1 = *reinterpret_cast<const bf16x8*>(xb + arow + 32);
        bf16x8 a2 = *reinterpret_cast<const bf16x8*>(h1b + arow);
        bf16x8 a3 = *reinterpret_cast<const bf16x8*>(h1b + arow + 32);
        f32x4 accj[4];
#pragma unroll
        for (int f = 0; f < 4; ++f) accj[f] = (f32x4){bsj[f], bsj[f], bsj[f], bsj[f]};
#pragma unroll
        for (int f = 0; f < 4; ++f) {
            accj[f] = __builtin_amdgcn_mfma_f32_16x16x32_bf16(a0, bjfrag[0][f], accj[f], 0, 0, 0);
            accj[f] = __builtin_amdgcn_mfma_f32_16x16x32_bf16(a1, bjfrag[1][f], accj[f], 0, 0, 0);
            accj[f] = __builtin_amdgcn_mfma_f32_16x16x32_bf16(a2, bjfrag[2][f], accj[f], 0, 0, 0);
            accj[f] = __builtin_amdgcn_mfma_f32_16x16x32_bf16(a3, bjfrag[3][f], accj[f], 0, 0, 0);
            accj[f] = __builtin_amdgcn_mfma_f32_16x16x32_bf16(a4, bjfrag[4][f], accj[f], 0, 0, 0);
            accj[f] = __builtin_amdgcn_mfma_f32_16x16x32_bf16(a5, bjfrag[5][f], accj[f], 0, 0, 0);
        }
#pragma unroll
        for (int f = 0; f < 4; ++f)
#pragma unroll
            for (int i = 0; i < 4; ++i)
                out[(size_t)(r0 + lhi * 4 + i) * 64 + f * 16 + l15] = accj[f][i];
    }
}

// ---------------- BN finalize: reduce SR_BLOCKS rows -> scale/shift ----------------
__global__ __launch_bounds__(1024) void bn_finalize_kernel(
        const float* __restrict__ stats_partial, int nblocks,
        const float* __restrict__ gamma, const float* __restrict__ beta,
        float* __restrict__ scale, float* __restrict__ shift) {
    __shared__ float red[2][1024];
    const int t = threadIdx.x;
    const int c = t & 63;
    const int chunk = t >> 6;        // 0..15
    float s = 0.f, q = 0.f;
    for (int b = chunk; b < nblocks; b += 16) {
        s += stats_partial[(size_t)b * 128 + c];
        q += stats_partial[(size_t)b * 128 + 64 + c];
    }
    red[0][t] = s;
    red[1][t] = q;
    __syncthreads();
    if (chunk == 0) {
        float ss = 0.f, qq = 0.f;
#pragma unroll
        for (int k = 0; k < 16; ++k) {
            ss += red[0][k * 64 + c];
            qq += red[1][k * 64 + c];
        }
        float mean = ss / (float)N_NODES;
        float var  = qq / (float)N_NODES - mean * mean;
        float scl  = gamma[c] * rsqrtf(var + BN_EPS);
        scale[c] = scl;
        shift[c] = beta[c] - mean * scl;
    }
}

extern "C" void kernel_launch(void* const* d_in, const int* in_sizes, int n_in,
                              void* d_out, int out_size, void* d_ws, size_t ws_size,
                              hipStream_t stream) {
    const float* x    = (const float*)d_in[0];
    const int*   ei   = (const int*)d_in[1];
    const int*   src  = ei;
    const int*   dst  = ei + N_EDGES;
    const float* W1_0 = (const float*)d_in[3];
    const float* b1_0 = (const float*)d_in[4];
    const float* g_0  = (const float*)d_in[5];
    const float* be_0 = (const float*)d_in[6];
    const float* W2_0 = (const float*)d_in[7];
    const float* b2_0 = (const float*)d_in[8];
    const float* W1_1 = (const float*)d_in[9];
    const float* b1_1 = (const float*)d_in[10];
    const float* g_1  = (const float*)d_in[11];
    const float* be_1 = (const float*)d_in[12];
    const float* W2_1 = (const float*)d_in[13];
    const float* b2_1 = (const float*)d_in[14];
    const float* Wjk  = (const float*)d_in[15];
    const float* bjk  = (const float*)d_in[16];

    const size_t FEAT = (size_t)N_NODES * HID;

    unsigned short* aggb = (unsigned short*)d_ws;          // FEAT bf16
    unsigned short* hb   = aggb + FEAT;                    // FEAT bf16
    unsigned short* xb   = hb + FEAT;                      // FEAT bf16
    unsigned short* h1b  = xb + FEAT;                      // FEAT bf16
    int*   bucketed = (int*)(h1b + FEAT);                  // N_EDGES
    float* stats  = (float*)(bucketed + N_EDGES);          // G1_BLOCKS * 128
    float* stats2 = stats + (size_t)G1_BLOCKS * 128;       // SR_BLOCKS * 128
    float* scale  = stats2 + (size_t)SR_BLOCKS * 128;
    float* shift  = scale + 64;
    int*   off   = (int*)(shift + 64);                     // N_NODES + 1 (pad 2)
    int*   eidx  = off + N_NODES + 2;                      // N_EDGES
    int*   cnt   = eidx + N_EDGES;                         // MS_CNT
    int*   psum  = cnt + MS_CNT;                           // MS_CNT (pad 2)
    int*   bsums = psum + MS_CNT + 2;                      // 1024
    unsigned short* wjk_t = (unsigned short*)(bsums + 1024);// 64*192
    unsigned short* w2t_0 = wjk_t + 64 * 192;              // 64*64
    unsigned short* w2t_1 = w2t_0 + 64 * 64;               // 64*64
    unsigned short* w1t_0 = w2t_1 + 64 * 64;               // 64*64
    unsigned short* w1t_1 = w1t_0 + 64 * 64;               // 64*64
    float* out   = (float*)d_out;

    // ---------------- prep: cvt + wtrans + hist in one launch ----------------
    prep_kernel<<<PREP_BLOCKS, 256, 0, stream>>>(
        x, xb, Wjk, W1_0, W2_0, W1_1, W2_1,
        wjk_t, w1t_0, w2t_0, w1t_1, w2t_1, dst, cnt);

    // ---------------- CSR build (addback folded into consumers) ----------------
    scan_partial_g<<<GS_BLOCKS, 256, 0, stream>>>(cnt, psum, bsums, MS_CNT);
    scan_bsums_kernel<<<1, 256, 0, stream>>>(bsums, GS_BLOCKS);
    msplit_scatter_kernel<<<MS_BLOCKS, 256, 0, stream>>>(src, dst, psum, bsums, bucketed);
    bucket_csr_kernel<<<NB, 256, 0, stream>>>(bucketed, psum, bsums, off, eidx);

    // ---------------- layer 0 ----------------
    gather_kernel<<<GATHER_BLOCKS, 256, 0, stream>>>(xb, off, eidx, aggb);
    gemm1_mfma_kernel<<<G1_BLOCKS, 256, 0, stream>>>(aggb, w1t_0, b1_0, hb, stats);
    stats_reduce_kernel<<<SR_BLOCKS, 256, 0, stream>>>(stats, stats2, G1_BLOCKS);
    bn_finalize_kernel<<<1, 1024, 0, stream>>>(stats2, SR_BLOCKS, g_0, be_0, scale, shift);
    bn_gemm_mfma_kernel<<<G2_BLOCKS, 256, 0, stream>>>(hb, w2t_0, b2_0, scale, shift, h1b);

    // ---------------- layer 1 (GEMM2 fused into jump head) ----------------
    gather_kernel<<<GATHER_BLOCKS, 256, 0, stream>>>(h1b, off, eidx, aggb);
    gemm1_mfma_kernel<<<G1_BLOCKS, 256, 0, stream>>>(aggb, w1t_1, b1_1, hb, stats);
    stats_reduce_kernel<<<SR_BLOCKS, 256, 0, stream>>>(stats, stats2, G1_BLOCKS);
    bn_finalize_kernel<<<1, 1024, 0, stream>>>(stats2, SR_BLOCKS, g_1, be_1, scale, shift);
    bn_gemm_jumphead_kernel<<<G2_BLOCKS, 256, 0, stream>>>(
        hb, w2t_1, b2_1, scale, shift, xb, h1b, wjk_t, bjk, out);
}